// Round 20
// baseline (424.723 us; speedup 1.0000x reference)
//
#include <hip/hip_runtime.h>
#include <cmath>

typedef _Float16 f16;
typedef _Float16 f16x4 __attribute__((ext_vector_type(4)));
typedef _Float16 f16x8 __attribute__((ext_vector_type(8)));
typedef float f32x4 __attribute__((ext_vector_type(4)));
typedef unsigned u32x4 __attribute__((ext_vector_type(4)));
typedef unsigned long long u64;

// Dims: V=32000 E=256 H=256 B=64 S=32 T=32; decoder hidden 2H=512.
static constexpr u64 SENT = 0xFFFFFFFFFFFFFFFFULL;  // f16x4 all-NaN; gate outputs never NaN

union V4 { u32x4 u; f16x8 h; };

typedef __attribute__((address_space(3))) void lds_t;
typedef const __attribute__((address_space(1))) void gbl_t;

// ---------------- workspace layout (bytes) ----------------
static constexpr size_t OFF_WIHF = 0;                                 // 768x256 f16
static constexpr size_t OFF_WHHF = OFF_WIHF + 768UL*256*2;
static constexpr size_t OFF_WIHB = OFF_WHHF + 768UL*256*2;
static constexpr size_t OFF_WHHB = OFF_WIHB + 768UL*256*2;
static constexpr size_t OFF_WIHD = OFF_WHHB + 768UL*256*2;            // 1536x768 f16
static constexpr size_t OFF_WHHD = OFF_WIHD + 1536UL*768*2;           // 1536x512 f16
static constexpr size_t OFF_FCW  = OFF_WHHD + 1536UL*512*2;           // 32000x512 f16
static constexpr size_t OFF_XENC = OFF_FCW  + 32000UL*512*2;          // 2048x256 f16
static constexpr size_t OFF_XDEC = OFF_XENC + 2048UL*256*2;           // 1984x256 f16
static constexpr size_t OFF_GIF  = OFF_XDEC + 1984UL*256*2;           // 2048x768 f32
static constexpr size_t OFF_GIB  = OFF_GIF  + 2048UL*768*4;
static constexpr size_t OFF_GITOK= OFF_GIB  + 2048UL*768*4;           // 1984x1536 f32
static constexpr size_t OFF_CTX16= OFF_GITOK+ 1984UL*1536*4;          // 64x512 f16
static constexpr size_t OFF_HPP  = OFF_CTX16+ 64UL*512*2;             // [2dir][32step][64][256] f16
static constexpr size_t OFF_HALL = OFF_HPP  + 2UL*32*64*256*2;        // [31+][64][512] f16

__device__ __forceinline__ float sigmoidf_(float x) {
  return __builtin_amdgcn_rcpf(1.f + __expf(-x));
}
__device__ __forceinline__ float tanhf_(float x) {
  float xc = fminf(fmaxf(x, -10.f), 10.f);
  float e = __expf(2.f * xc);
  return (e - 1.f) * __builtin_amdgcn_rcpf(e + 1.f);
}

__device__ __forceinline__ void wait_vm0() {
  asm volatile("s_waitcnt vmcnt(0)" ::: "memory");
  __builtin_amdgcn_sched_barrier(0);
}
// producer h store: 8B relaxed agent atomic (write-through to L3); fire-and-forget
__device__ __forceinline__ void sth4(f16* p, float a, float b, float c, float d) {
  union { u64 u; f16 h[4]; } t;
  t.h[0] = (f16)a; t.h[1] = (f16)b; t.h[2] = (f16)c; t.h[3] = (f16)d;
  __hip_atomic_store((u64*)p, t.u, __ATOMIC_RELAXED, __HIP_MEMORY_SCOPE_AGENT);
}

// ---------------- K1: init (gather + SMALL weight convert + sentinel fills) ----------------
// fcw conversion moved to k_gi (overlaps the input GEMMs; both pure-BW).
__global__ void k_init(const int* __restrict__ srct, const int* __restrict__ trgt,
                       const float* __restrict__ embe, const float* __restrict__ embd,
                       const float* __restrict__ wihf, const float* __restrict__ whhf,
                       const float* __restrict__ wihb, const float* __restrict__ whhb,
                       const float* __restrict__ wihd, const float* __restrict__ whhd,
                       f16* dWihf, f16* dWhhf, f16* dWihb, f16* dWhhb,
                       f16* dWihd, f16* dWhhd,
                       f16* __restrict__ Xenc, f16* __restrict__ Xdec,
                       f16* __restrict__ hpp, f16* __restrict__ Hall,
                       f16* __restrict__ ctx16) {
  int b = blockIdx.x, tid = threadIdx.x;
  if (b < 1024) {
    long t = (long)b * 256 + tid;       // [0, 262144)
    const long stride = 1024L * 256;
    for (long i = t; i < 4032L * 64; i += stride) {
      int row = (int)(i >> 6), j4 = (int)(i & 63);
      const float* e; f16* d; int tok;
      if (row < 2048) {
        int s = row >> 6, bb = row & 63;
        tok = srct[bb * 32 + s]; e = embe; d = Xenc + (long)row * 256;
      } else {
        int rd = row - 2048; int tt = rd >> 6, bb = rd & 63;
        tok = trgt[bb * 32 + tt]; e = embd; d = Xdec + (long)rd * 256;
      }
      float4 v = ((const float4*)(e + (long)tok * 256))[j4];
      f16x4 o; o.x = (f16)v.x; o.y = (f16)v.y; o.z = (f16)v.z; o.w = (f16)v.w;
      ((f16x4*)d)[j4] = o;
    }
    // sentinel Hall slots 0..30 (re-done EVERY launch; graph replays reuse ws)
    u64* H8 = (u64*)Hall;
    if (t < 253952) H8[t] = SENT;
    // hpp: step-0 buffers zero; steps 1..31 sentinel. dir stride 131072 u64.
    u64* P8 = (u64*)hpp;
    if (t < 4096) { P8[t] = 0ULL; P8[131072 + t] = 0ULL; }
    if (t < 126976) { P8[4096 + t] = SENT; P8[131072 + 4096 + t] = SENT; }
    // ctx16 sentinel (64x512 f16 = 8192 u64)
    u64* C8 = (u64*)ctx16;
    if (t < 8192) C8[t] = SENT;
  } else {
    // small-weight fp32->f16 conversion: 688128 float4 granules, 1 per thread
    long j = (long)(b - 1024) * 256 + tid;   // [0, 688128)
    const float* s; f16* d;
    if (j < 49152L)        { s = wihf; d = dWihf; }
    else if (j < 98304L)   { s = whhf; d = dWhhf; j -= 49152L; }
    else if (j < 147456L)  { s = wihb; d = dWihb; j -= 98304L; }
    else if (j < 196608L)  { s = whhb; d = dWhhb; j -= 147456L; }
    else if (j < 491520L)  { s = wihd; d = dWihd; j -= 196608L; }
    else                   { s = whhd; d = dWhhd; j -= 491520L; }
    float4 v = ((const float4*)s)[j];
    f16x4 o; o.x = (f16)v.x; o.y = (f16)v.y; o.z = (f16)v.z; o.w = (f16)v.w;
    ((f16x4*)d)[j] = o;
  }
}

// ---------------- shared GEMM body: C[M,N] = A[M,K]f16 @ B[N,K]f16^T (+bias) ----------------
__device__ __forceinline__ void gemm_body(int bx, int by,
                                          const f16* __restrict__ A, int lda,
                                          const f16* __restrict__ B, int ldb,
                                          const float* __restrict__ bias,
                                          float* __restrict__ C, int ldc, int Ksteps) {
  int m0 = bx * 64, n0 = by * 64;
  int lane = threadIdx.x & 63, w = threadIdx.x >> 6;
  int ar = m0 + w * 16 + (lane & 15);
  int koff = (lane >> 4) * 8;
  f32x4 acc[4] = {};
  for (int ks = 0; ks < Ksteps; ks++) {
    f16x8 a = *(const f16x8*)(A + (size_t)ar * lda + ks * 32 + koff);
#pragma unroll
    for (int ni = 0; ni < 4; ni++) {
      const f16* bp = B + (size_t)(n0 + ni * 16 + (lane & 15)) * ldb + ks * 32 + koff;
      f16x8 bfr = *(const f16x8*)bp;
      acc[ni] = __builtin_amdgcn_mfma_f32_16x16x32_f16(a, bfr, acc[ni], 0, 0, 0);
    }
  }
  int dm = m0 + w * 16 + ((lane >> 4) << 2);
  int dn0 = n0 + (lane & 15);
#pragma unroll
  for (int ni = 0; ni < 4; ni++) {
    int n = dn0 + ni * 16;
    float bv = bias ? bias[n] : 0.f;
#pragma unroll
    for (int r = 0; r < 4; r++) C[(size_t)(dm + r) * ldc + n] = acc[ni][r] + bv;
  }
}

// ---------------- K2: input GEMMs (giF|giB|giTok) + out[:,0,:] zero + fcw convert ----------------
__global__ __launch_bounds__(256) void k_gi(const f16* __restrict__ Xenc, const f16* __restrict__ Xdec,
                                            const f16* __restrict__ Wf, const f16* __restrict__ Wb,
                                            const f16* __restrict__ Wd,
                                            const float* __restrict__ bf, const float* __restrict__ bb,
                                            float* __restrict__ giF, float* __restrict__ giB,
                                            float* __restrict__ giTok, float* __restrict__ out,
                                            const float* __restrict__ fcw, f16* __restrict__ Wfc) {
  int b = blockIdx.x;
  if (b < 384)      gemm_body(b & 31, b >> 5, Xenc, 256, Wf, 256, bf, giF, 768, 8);
  else if (b < 768) { b -= 384; gemm_body(b & 31, b >> 5, Xenc, 256, Wb, 256, bb, giB, 768, 8); }
  else if (b < 1512) { b -= 768; gemm_body(b % 31, b / 31, Xdec, 256, Wd, 768, nullptr, giTok, 1536, 8); }
  else if (b < 1637) {
    // zero out[:, 0, :]: 64 rows x 8000 float4 = 512000 float4; 125 blocks x 256 thr x 16
    long t = (long)(b - 1512) * 256 + threadIdx.x;
    float4 z = make_float4(0.f, 0.f, 0.f, 0.f);
#pragma unroll
    for (int k = 0; k < 16; k++) {
      long i = t * 16 + k;
      long bb = i / 8000, j = i % 8000;
      ((float4*)(out + bb * 1024000L))[j] = z;
    }
  } else {
    // fcw fp32->f16: 4,096,000 float4 granules over 128 blocks (125/thread)
    long t = (long)(b - 1637) * 256 + threadIdx.x;   // [0, 32768)
    for (long i = t; i < 4096000L; i += 32768L) {
      float4 v = ((const float4*)fcw)[i];
      f16x4 o; o.x = (f16)v.x; o.y = (f16)v.y; o.z = (f16)v.z; o.w = (f16)v.w;
      ((f16x4*)Wfc)[i] = o;
    }
  }
}

// ---------------- K3: fused enc (WGs 0..15) + dec (WGs 16..47) ----------------
__device__ __forceinline__ void enc_body(
    f16* W,
    const float* __restrict__ giF, const float* __restrict__ giB,
    const f16* __restrict__ WhhF, const f16* __restrict__ WhhB,
    const float* __restrict__ bhhF, const float* __restrict__ bhhB,
    f16* __restrict__ hpp, f16* __restrict__ ctx16) {
  int wg = blockIdx.x;
  int dir = wg >> 3, ns = wg & 7;
  int tid = threadIdx.x, lane = tid & 63, wv = tid >> 6;
  int mTile = wv;
  const float* gi = dir ? giB : giF;
  const f16* Whh = dir ? WhhB : WhhF;
  const float* bhh = dir ? bhhB : bhhF;
  f16* hb = hpp + (size_t)dir * (32 * 64 * 256);
  int lo = lane & 15, hi = lane >> 4;
  int m = mTile * 16 + lo;
  int jb0 = ns * 32 + hi * 4;

#pragma unroll
  for (int c = 0; c < 12; c++) {
    int seg = c * 256 + tid;
    int row = seg >> 5, ck = seg & 31;
    int q = row >> 5, ii = row & 31;
    f16x8 v = *(const f16x8*)(Whh + (size_t)(q * 256 + ns * 32 + ii) * 256 + ck * 8);
    int col = (ck * 8) ^ ((row & 7) << 3);
    *(f16x8*)&W[row * 256 + col] = v;
  }
  __syncthreads();

  float4 bh[3][2];
#pragma unroll
  for (int q = 0; q < 3; q++)
#pragma unroll
    for (int i = 0; i < 2; i++)
      bh[q][i] = *(const float4*)(bhh + q * 256 + jb0 + i * 16);

  float4 ho[2] = {};
  float4 gcur[3][2];
  {
    int s0 = dir ? 31 : 0;
    const float* g0 = gi + (size_t)s0 * (64 * 768);
#pragma unroll
    for (int q = 0; q < 3; q++)
#pragma unroll
      for (int i = 0; i < 2; i++)
        gcur[q][i] = *(const float4*)(g0 + (size_t)m * 768 + q * 256 + jb0 + i * 16);
  }

  for (int s = 0; s < 32; s++) {
    // speculative burst: load own h[s] slice immediately; retry whole burst on sentinel
    V4 hv[8];
    const char* hb8 = (const char*)hb + ((size_t)s * 16384 + (size_t)m * 256 + hi * 8) * 2;
    for (;;) {
#pragma unroll
      for (int ks = 0; ks < 8; ks++)
        asm volatile("global_load_dwordx4 %0, %1, off offset:%2 sc0 sc1"
                     : "=&v"(hv[ks].u) : "v"(hb8), "i"(ks * 64));
      wait_vm0();
      unsigned bad = 0;
#pragma unroll
      for (int ks = 0; ks < 8; ks++) {
        bad |= ((hv[ks].u.x & hv[ks].u.y) == 0xFFFFFFFFu);
        bad |= ((hv[ks].u.z & hv[ks].u.w) == 0xFFFFFFFFu);
      }
      if (!__any((int)bad)) break;
      __builtin_amdgcn_s_sleep(1);
    }
    f32x4 acc[3][2] = {};
#pragma unroll
    for (int ks = 0; ks < 8; ks++) {
#pragma unroll
      for (int q = 0; q < 3; q++)
#pragma unroll
        for (int i = 0; i < 2; i++) {
          int row = q * 32 + i * 16 + lo;
          int col = (ks * 32 + hi * 8) ^ ((row & 7) << 3);
          f16x8 w = *(const f16x8*)&W[row * 256 + col];
          acc[q][i] = __builtin_amdgcn_mfma_f32_16x16x32_f16(w, hv[ks].h, acc[q][i], 0, 0, 0);
        }
    }
#pragma unroll
    for (int i = 0; i < 2; i++) {
      float hvv[4];
#pragma unroll
      for (int r2 = 0; r2 < 4; r2++) {
        float rg = sigmoidf_(((const float*)&gcur[0][i])[r2] + acc[0][i][r2] + ((const float*)&bh[0][i])[r2]);
        float zg = sigmoidf_(((const float*)&gcur[1][i])[r2] + acc[1][i][r2] + ((const float*)&bh[1][i])[r2]);
        float ng = tanhf_(((const float*)&gcur[2][i])[r2] + rg * (acc[2][i][r2] + ((const float*)&bh[2][i])[r2]));
        float hprev = ((const float*)&ho[i])[r2];
        hvv[r2] = (1.f - zg) * ng + zg * hprev;
        ((float*)&ho[i])[r2] = hvv[r2];
      }
      if (s < 31) sth4(hb + (size_t)(s + 1) * 16384 + m * 256 + jb0 + i * 16,
                       hvv[0], hvv[1], hvv[2], hvv[3]);
    }
    if (s < 31) {
      int sn = s + 1;
      int sgin = dir ? (31 - sn) : sn;
      const float* gs = gi + (size_t)sgin * (64 * 768);
#pragma unroll
      for (int q = 0; q < 3; q++)
#pragma unroll
        for (int i = 0; i < 2; i++)
          gcur[q][i] = *(const float4*)(gs + (size_t)m * 768 + q * 256 + jb0 + i * 16);
    }
  }
  // final context -> ctx16 via agent-scope 8B atomic stores (dec spins on these)
#pragma unroll
  for (int i = 0; i < 2; i++) {
    int c = dir * 256 + jb0 + i * 16;
    sth4(ctx16 + m * 512 + c, ((const float*)&ho[i])[0], ((const float*)&ho[i])[1],
         ((const float*)&ho[i])[2], ((const float*)&ho[i])[3]);
  }
}

__device__ __forceinline__ void dec_body(
    f16* W,
    const float* __restrict__ giTok, const f16* __restrict__ Wihd, const float* __restrict__ bihd,
    const f16* __restrict__ Whh, const float* __restrict__ bhh,
    const f16* __restrict__ ctx16, f16* __restrict__ Hall) {
  int cg = blockIdx.x - 16;
  int tid = threadIdx.x, lane = tid & 63, wv = tid >> 6;
  int mTile = wv;
  int lo = lane & 15, hi = lane >> 4;
  int koff = hi * 8;
  int m = mTile * 16 + lo;
  int j0 = cg * 16 + hi * 4;

  // stage weights (independent of enc -> overlaps encoder execution)
#pragma unroll
  for (int c = 0; c < 12; c++) {
    int seg = c * 256 + tid;
    int row = seg >> 6, ck = seg & 63;
    int q = row >> 4, ii = row & 15;
    f16x8 v = *(const f16x8*)(Whh + (size_t)(q * 512 + cg * 16 + ii) * 512 + ck * 8);
    int col = (ck * 8) ^ ((row & 7) << 3);
    *(f16x8*)&W[row * 512 + col] = v;
  }
  // biases + t=0 gi (independent of enc)
  float bi0[4], bi1[4], bi2[4], bh0[4], bh1[4], bhn[4];
#pragma unroll
  for (int r2 = 0; r2 < 4; r2++) {
    bi0[r2] = bihd[j0 + r2];        bh0[r2] = bhh[j0 + r2];
    bi1[r2] = bihd[512 + j0 + r2];  bh1[r2] = bhh[512 + j0 + r2];
    bi2[r2] = bihd[1024 + j0 + r2]; bhn[r2] = bhh[1024 + j0 + r2];
  }
  float4 gcur[3];
#pragma unroll
  for (int q = 0; q < 3; q++)
    gcur[q] = *(const float4*)(giTok + (size_t)m * 1536 + q * 512 + j0);
  __syncthreads();                        // weights staged

  // wait for ctx16 row m: speculative burst + sentinel retry (long-wait backoff)
  V4 hv[16];
  {
    const char* cb8 = (const char*)ctx16 + ((size_t)m * 512 + hi * 8) * 2;
    for (;;) {
#pragma unroll
      for (int ks = 0; ks < 16; ks++)
        asm volatile("global_load_dwordx4 %0, %1, off offset:%2 sc0 sc1"
                     : "=&v"(hv[ks].u) : "v"(cb8), "i"(ks * 64));
      wait_vm0();
      unsigned bad = 0;
#pragma unroll
      for (int ks = 0; ks < 16; ks++) {
        bad |= ((hv[ks].u.x & hv[ks].u.y) == 0xFFFFFFFFu);
        bad |= ((hv[ks].u.z & hv[ks].u.w) == 0xFFFFFFFFu);
      }
      if (!__any((int)bad)) break;
      __builtin_amdgcn_s_sleep(32);
    }
  }
  // ho init from ctx16 (f16-derived; one-time rounding, within tolerance)
  float4 ho;
  {
    u64 hoq;
    const u64* hp = (const u64*)(ctx16 + (size_t)m * 512 + j0);
    asm volatile("global_load_dwordx2 %0, %1, off sc0 sc1" : "=v"(hoq) : "v"(hp));
    asm volatile("s_waitcnt vmcnt(0)" ::: "memory");
    union { u64 u; f16 h[4]; } hu; hu.u = hoq;
    ho = make_float4((float)hu.h[0], (float)hu.h[1], (float)hu.h[2], (float)hu.h[3]);
  }
  // giCtx = ctx @ W_ihd[:,256:].T via MFMA (reuses hv as the A-operand)
  f32x4 acx[3] = {};
#pragma unroll
  for (int ks = 0; ks < 16; ks++) {
#pragma unroll
    for (int q = 0; q < 3; q++) {
      f16x8 w = *(const f16x8*)(Wihd + (size_t)(q * 512 + cg * 16 + lo) * 768 + 256 + ks * 32 + koff);
      acx[q] = __builtin_amdgcn_mfma_f32_16x16x32_f16(w, hv[ks].h, acx[q], 0, 0, 0);
    }
  }
  float b0[4], b1[4], bo2[4];
#pragma unroll
  for (int r2 = 0; r2 < 4; r2++) {
    b0[r2]  = acx[0][r2] + bi0[r2] + bh0[r2];
    b1[r2]  = acx[1][r2] + bi1[r2] + bh1[r2];
    bo2[r2] = acx[2][r2] + bi2[r2];
  }

  const int pj = lane >> 1;
  const int prow = mTile * 16 + (lane & 1) * 8;

  for (int t = 0; t < 31; t++) {
    if (t > 0) {
      // 1) cheap readiness probe (512B per wave per pass)
      {
        const u64* gp = (const u64*)(Hall + (size_t)(t - 1) * 32768) + (size_t)prow * 128 + pj * 4;
        for (;;) {
          u64 v;
          asm volatile("global_load_dwordx2 %0, %1, off sc0 sc1" : "=v"(v) : "v"(gp));
          asm volatile("s_waitcnt vmcnt(0)" ::: "memory");
          if (__all((int)(v != SENT))) break;
          __builtin_amdgcn_s_sleep(1);
        }
        __builtin_amdgcn_sched_barrier(0);
      }
      // 2) full burst, sentinel-validated
      const char* hb8 = (const char*)Hall + ((size_t)(t - 1) * 32768 + (size_t)m * 512 + hi * 8) * 2;
      for (;;) {
#pragma unroll
        for (int ks = 0; ks < 16; ks++)
          asm volatile("global_load_dwordx4 %0, %1, off offset:%2 sc0 sc1"
                       : "=&v"(hv[ks].u) : "v"(hb8), "i"(ks * 64));
        wait_vm0();
        unsigned bad = 0;
#pragma unroll
        for (int ks = 0; ks < 16; ks++) {
          bad |= ((hv[ks].u.x & hv[ks].u.y) == 0xFFFFFFFFu);
          bad |= ((hv[ks].u.z & hv[ks].u.w) == 0xFFFFFFFFu);
        }
        if (!__any((int)bad)) break;
        __builtin_amdgcn_s_sleep(1);
      }
    }
    f32x4 acc[3] = {};
#pragma unroll
    for (int ks = 0; ks < 16; ks++) {
#pragma unroll
      for (int q = 0; q < 3; q++) {
        int row = q * 16 + lo;
        int col = (ks * 32 + hi * 8) ^ ((row & 7) << 3);
        f16x8 w = *(const f16x8*)&W[row * 512 + col];
        acc[q] = __builtin_amdgcn_mfma_f32_16x16x32_f16(w, hv[ks].h, acc[q], 0, 0, 0);
      }
    }
    float hvv[4];
#pragma unroll
    for (int r2 = 0; r2 < 4; r2++) {
      float rg = sigmoidf_(((const float*)&gcur[0])[r2] + acc[0][r2] + b0[r2]);
      float zg = sigmoidf_(((const float*)&gcur[1])[r2] + acc[1][r2] + b1[r2]);
      float ng = tanhf_(((const float*)&gcur[2])[r2] + bo2[r2] + rg * (acc[2][r2] + bhn[r2]));
      float hprev = ((const float*)&ho)[r2];
      hvv[r2] = (1.f - zg) * ng + zg * hprev;
      ((float*)&ho)[r2] = hvv[r2];
    }
    sth4(Hall + (size_t)t * 32768 + (size_t)m * 512 + j0, hvv[0], hvv[1], hvv[2], hvv[3]);
    // prefetch next token-gi (overlaps store latency + next poll)
    {
      int tn = (t + 1 < 31) ? t + 1 : 30;
      const float* gs = giTok + (size_t)tn * (64 * 1536);
#pragma unroll
      for (int q = 0; q < 3; q++)
        gcur[q] = *(const float4*)(gs + (size_t)m * 1536 + q * 512 + j0);
    }
  }
}

__global__ __launch_bounds__(256, 1) void k_encdec(
    const float* __restrict__ giF, const float* __restrict__ giB,
    const f16* __restrict__ WhhF, const f16* __restrict__ WhhB,
    const float* __restrict__ bhhF, const float* __restrict__ bhhB,
    f16* __restrict__ hpp, f16* __restrict__ ctx16,
    const float* __restrict__ giTok, const f16* __restrict__ Wihd, const float* __restrict__ bihd,
    const f16* __restrict__ Whhd, const float* __restrict__ bhhd,
    f16* __restrict__ Hall) {
  __shared__ f16 W[96 * 256];   // 48KB: enc 96x256, dec 48x512 (same size)
  if (blockIdx.x < 16)
    enc_body(W, giF, giB, WhhF, WhhB, bhhF, bhhB, hpp, ctx16);
  else
    dec_body(W, giTok, Wihd, bihd, Whhd, bhhd, ctx16, Hall);
}

// ---------------- K4: FC GEMM (m97 staging, col-grouped, scalar NT stores; 3 blocks/CU) ----------------
__global__ __launch_bounds__(256, 3) void k_fc(const f16* __restrict__ Hall, const f16* __restrict__ Wfc,
                                               const float* __restrict__ fcb, float* __restrict__ out) {
  __shared__ f16 As[128 * 64];
  __shared__ f16 Bs[128 * 64];
  int bid = blockIdx.x;
  int bx = bid >> 4;                     // 0..249  column block
  int by = bid & 15;                     // 0..15   row block
  int m0 = by * 128, n0 = bx * 128;
  int tid = threadIdx.x, lane = tid & 63, wv = tid >> 6;
  int wm = wv >> 1, wn = wv & 1;
  int lo = lane & 15, hi = lane >> 4;
  int srow = lane >> 3, scol = (lane & 7) * 8;
  f32x4 acc[4][4] = {};
  for (int kk = 0; kk < 8; kk++) {
    if (kk) __syncthreads();
#pragma unroll
    for (int c4 = 0; c4 < 4; c4++) {
      int c = wv * 4 + c4;
      const f16* sA = Hall + (size_t)(m0 + c * 8 + srow) * 512 + kk * 64 + scol;
      const f16* sB = Wfc  + (size_t)(n0 + c * 8 + srow) * 512 + kk * 64 + scol;
      __builtin_amdgcn_global_load_lds((gbl_t*)sA, (lds_t*)&As[c * 512], 16, 0, 0);
      __builtin_amdgcn_global_load_lds((gbl_t*)sB, (lds_t*)&Bs[c * 512], 16, 0, 0);
    }
    __syncthreads();
#pragma unroll
    for (int ks = 0; ks < 2; ks++) {
      f16x8 af[4], bf[4];
#pragma unroll
      for (int mi = 0; mi < 4; mi++)
        af[mi] = *(const f16x8*)&As[(wm * 64 + mi * 16 + lo) * 64 + ks * 32 + hi * 8];
#pragma unroll
      for (int ni = 0; ni < 4; ni++)
        bf[ni] = *(const f16x8*)&Bs[(wn * 64 + ni * 16 + lo) * 64 + ks * 32 + hi * 8];
#pragma unroll
      for (int mi = 0; mi < 4; mi++) {
#pragma unroll
        for (int ni = 0; ni < 4; ni++)
          acc[mi][ni] = __builtin_amdgcn_mfma_f32_16x16x32_f16(af[mi], bf[ni], acc[mi][ni], 0, 0, 0);
      }
    }
  }
  int dn0 = n0 + wn * 64 + lo;
  float bv[4];
#pragma unroll
  for (int ni = 0; ni < 4; ni++) bv[ni] = fcb[dn0 + ni * 16];
#pragma unroll
  for (int mi = 0; mi < 4; mi++) {
    int mbase = m0 + wm * 64 + mi * 16 + (hi << 2);
#pragma unroll
    for (int rr = 0; rr < 4; rr++) {
      int mm = mbase + rr;
      if (mm < 1984) {
        int t = mm >> 6, bb = mm & 63;
        float* orow = out + (size_t)bb * 1024000 + (size_t)(t + 1) * 32000;
#pragma unroll
        for (int ni = 0; ni < 4; ni++)
          __builtin_nontemporal_store(acc[mi][ni][rr] + bv[ni], orow + dn0 + ni * 16);
      }
    }
  }
}

extern "C" void kernel_launch(void* const* d_in, const int* in_sizes, int n_in,
                              void* d_out, int out_size, void* d_ws, size_t ws_size,
                              hipStream_t stream) {
  const int*   srct = (const int*)d_in[0];
  const int*   trgt = (const int*)d_in[1];
  const float* embe = (const float*)d_in[2];
  const float* wihf = (const float*)d_in[3];
  const float* whhf = (const float*)d_in[4];
  const float* bihf = (const float*)d_in[5];
  const float* bhhf = (const float*)d_in[6];
  const float* wihb = (const float*)d_in[7];
  const float* whhb = (const float*)d_in[8];
  const float* bihb = (const float*)d_in[9];
  const float* bhhb = (const float*)d_in[10];
  const float* embd = (const float*)d_in[11];
  const float* wihd = (const float*)d_in[12];
  const float* whhd = (const float*)d_in[13];
  const float* bihd = (const float*)d_in[14];
  const float* bhhd = (const float*)d_in[15];
  const float* fcw  = (const float*)d_in[16];
  const float* fcb  = (const float*)d_in[17];
  float* out = (float*)d_out;
  char* ws = (char*)d_ws;

  f16* W_ihf = (f16*)(ws + OFF_WIHF);
  f16* W_hhf = (f16*)(ws + OFF_WHHF);
  f16* W_ihb = (f16*)(ws + OFF_WIHB);
  f16* W_hhb = (f16*)(ws + OFF_WHHB);
  f16* W_ihd = (f16*)(ws + OFF_WIHD);
  f16* W_hhd = (f16*)(ws + OFF_WHHD);
  f16* Wfc   = (f16*)(ws + OFF_FCW);
  f16* Xenc  = (f16*)(ws + OFF_XENC);
  f16* Xdec  = (f16*)(ws + OFF_XDEC);
  float* giF   = (float*)(ws + OFF_GIF);
  float* giB   = (float*)(ws + OFF_GIB);
  float* giTok = (float*)(ws + OFF_GITOK);
  f16*   ctx16 = (f16*)(ws + OFF_CTX16);
  f16*   hpp   = (f16*)(ws + OFF_HPP);
  f16*   Hall  = (f16*)(ws + OFF_HALL);

  k_init<<<3712, 256, 0, stream>>>(srct, trgt, embe, embd,
                                   wihf, whhf, wihb, whhb, wihd, whhd,
                                   W_ihf, W_hhf, W_ihb, W_hhb, W_ihd, W_hhd,
                                   Xenc, Xdec, hpp, Hall, ctx16);
  k_gi<<<1765, 256, 0, stream>>>(Xenc, Xdec, W_ihf, W_ihb, W_ihd, bihf, bihb,
                                 giF, giB, giTok, out, fcw, Wfc);
  k_encdec<<<48, 256, 0, stream>>>(giF, giB, W_hhf, W_hhb, bhhf, bhhb, hpp, ctx16,
                                   giTok, W_ihd, bihd, W_hhd, bhhd, Hall);
  k_fc<<<4000, 256, 0, stream>>>(Hall, Wfc, fcb, out);
}

// Round 21
// 406.753 us; speedup vs baseline: 1.0442x; 1.0442x over previous
//
#include <hip/hip_runtime.h>
#include <cmath>

typedef _Float16 f16;
typedef _Float16 f16x4 __attribute__((ext_vector_type(4)));
typedef _Float16 f16x8 __attribute__((ext_vector_type(8)));
typedef float f32x4 __attribute__((ext_vector_type(4)));
typedef unsigned u32x4 __attribute__((ext_vector_type(4)));
typedef unsigned long long u64;

// Dims: V=32000 E=256 H=256 B=64 S=32 T=32; decoder hidden 2H=512.
static constexpr u64 SENT = 0xFFFFFFFFFFFFFFFFULL;  // f16x4 all-NaN; gate outputs never NaN

union V4 { u32x4 u; f16x8 h; };

typedef __attribute__((address_space(3))) void lds_t;
typedef const __attribute__((address_space(1))) void gbl_t;

// ---------------- workspace layout (bytes) ----------------
static constexpr size_t OFF_WIHF = 0;                                 // 768x256 f16
static constexpr size_t OFF_WHHF = OFF_WIHF + 768UL*256*2;
static constexpr size_t OFF_WIHB = OFF_WHHF + 768UL*256*2;
static constexpr size_t OFF_WHHB = OFF_WIHB + 768UL*256*2;
static constexpr size_t OFF_WIHD = OFF_WHHB + 768UL*256*2;            // 1536x768 f16
static constexpr size_t OFF_WHHD = OFF_WIHD + 1536UL*768*2;           // 1536x512 f16
static constexpr size_t OFF_FCW  = OFF_WHHD + 1536UL*512*2;           // 32000x512 f16
static constexpr size_t OFF_XENC = OFF_FCW  + 32000UL*512*2;          // 2048x256 f16
static constexpr size_t OFF_XDEC = OFF_XENC + 2048UL*256*2;           // 1984x256 f16
static constexpr size_t OFF_GIF  = OFF_XDEC + 1984UL*256*2;           // 2048x768 f32
static constexpr size_t OFF_GIB  = OFF_GIF  + 2048UL*768*4;
static constexpr size_t OFF_GITOK= OFF_GIB  + 2048UL*768*4;           // 1984x1536 f32
static constexpr size_t OFF_CTX16= OFF_GITOK+ 1984UL*1536*4;          // 64x512 f16
static constexpr size_t OFF_HPP  = OFF_CTX16+ 64UL*512*2;             // [2dir][32step][64][256] f16
static constexpr size_t OFF_HALL = OFF_HPP  + 2UL*32*64*256*2;        // [31+][64][512] f16

__device__ __forceinline__ float sigmoidf_(float x) {
  return __builtin_amdgcn_rcpf(1.f + __expf(-x));
}
__device__ __forceinline__ float tanhf_(float x) {
  float xc = fminf(fmaxf(x, -10.f), 10.f);
  float e = __expf(2.f * xc);
  return (e - 1.f) * __builtin_amdgcn_rcpf(e + 1.f);
}

__device__ __forceinline__ void wait_vm0() {
  asm volatile("s_waitcnt vmcnt(0)" ::: "memory");
  __builtin_amdgcn_sched_barrier(0);
}
// producer h store: 8B relaxed agent atomic (write-through to L3); fire-and-forget
__device__ __forceinline__ void sth4(f16* p, float a, float b, float c, float d) {
  union { u64 u; f16 h[4]; } t;
  t.h[0] = (f16)a; t.h[1] = (f16)b; t.h[2] = (f16)c; t.h[3] = (f16)d;
  __hip_atomic_store((u64*)p, t.u, __ATOMIC_RELAXED, __HIP_MEMORY_SCOPE_AGENT);
}

// ---------------- K1: init (gather + weight convert + sentinel fills) ----------------
__global__ void k_init(const int* __restrict__ srct, const int* __restrict__ trgt,
                       const float* __restrict__ embe, const float* __restrict__ embd,
                       const float* __restrict__ wihf, const float* __restrict__ whhf,
                       const float* __restrict__ wihb, const float* __restrict__ whhb,
                       const float* __restrict__ wihd, const float* __restrict__ whhd,
                       const float* __restrict__ fcw,
                       f16* dWihf, f16* dWhhf, f16* dWihb, f16* dWhhb,
                       f16* dWihd, f16* dWhhd, f16* dFcw,
                       f16* __restrict__ Xenc, f16* __restrict__ Xdec,
                       f16* __restrict__ hpp, f16* __restrict__ Hall,
                       f16* __restrict__ ctx16) {
  int b = blockIdx.x, tid = threadIdx.x;
  if (b < 1024) {
    long t = (long)b * 256 + tid;       // [0, 262144)
    const long stride = 1024L * 256;
    for (long i = t; i < 4032L * 64; i += stride) {
      int row = (int)(i >> 6), j4 = (int)(i & 63);
      const float* e; f16* d; int tok;
      if (row < 2048) {
        int s = row >> 6, bb = row & 63;
        tok = srct[bb * 32 + s]; e = embe; d = Xenc + (long)row * 256;
      } else {
        int rd = row - 2048; int tt = rd >> 6, bb = rd & 63;
        tok = trgt[bb * 32 + tt]; e = embd; d = Xdec + (long)rd * 256;
      }
      float4 v = ((const float4*)(e + (long)tok * 256))[j4];
      f16x4 o; o.x = (f16)v.x; o.y = (f16)v.y; o.z = (f16)v.z; o.w = (f16)v.w;
      ((f16x4*)d)[j4] = o;
    }
    // sentinel Hall slots 0..30 (re-done EVERY launch; graph replays reuse ws)
    u64* H8 = (u64*)Hall;
    if (t < 253952) H8[t] = SENT;
    // hpp: step-0 buffers zero; steps 1..31 sentinel. dir stride 131072 u64.
    u64* P8 = (u64*)hpp;
    if (t < 4096) { P8[t] = 0ULL; P8[131072 + t] = 0ULL; }
    if (t < 126976) { P8[4096 + t] = SENT; P8[131072 + 4096 + t] = SENT; }
    // ctx16 sentinel (64x512 f16 = 8192 u64)
    u64* C8 = (u64*)ctx16;
    if (t < 8192) C8[t] = SENT;
  } else {
    long cb = b - 1024;                  // [0, 4672)
    const long stride = 4672L * 256;
    for (long i = cb * 256 + tid; i < 4784128L; i += stride) {
      const float* s; f16* d; long j = i;
      if (j < 49152L)        { s = wihf; d = dWihf; }
      else if (j < 98304L)   { s = whhf; d = dWhhf; j -= 49152L; }
      else if (j < 147456L)  { s = wihb; d = dWihb; j -= 98304L; }
      else if (j < 196608L)  { s = whhb; d = dWhhb; j -= 147456L; }
      else if (j < 491520L)  { s = wihd; d = dWihd; j -= 196608L; }
      else if (j < 688128L)  { s = whhd; d = dWhhd; j -= 491520L; }
      else                   { s = fcw;  d = dFcw;  j -= 688128L; }
      float4 v = ((const float4*)s)[j];
      f16x4 o; o.x = (f16)v.x; o.y = (f16)v.y; o.z = (f16)v.z; o.w = (f16)v.w;
      ((f16x4*)d)[j] = o;
    }
  }
}

// ---------------- shared GEMM body: C[M,N] = A[M,K]f16 @ B[N,K]f16^T (+bias) ----------------
__device__ __forceinline__ void gemm_body(int bx, int by,
                                          const f16* __restrict__ A, int lda,
                                          const f16* __restrict__ B, int ldb,
                                          const float* __restrict__ bias,
                                          float* __restrict__ C, int ldc, int Ksteps) {
  int m0 = bx * 64, n0 = by * 64;
  int lane = threadIdx.x & 63, w = threadIdx.x >> 6;
  int ar = m0 + w * 16 + (lane & 15);
  int koff = (lane >> 4) * 8;
  f32x4 acc[4] = {};
  for (int ks = 0; ks < Ksteps; ks++) {
    f16x8 a = *(const f16x8*)(A + (size_t)ar * lda + ks * 32 + koff);
#pragma unroll
    for (int ni = 0; ni < 4; ni++) {
      const f16* bp = B + (size_t)(n0 + ni * 16 + (lane & 15)) * ldb + ks * 32 + koff;
      f16x8 bfr = *(const f16x8*)bp;
      acc[ni] = __builtin_amdgcn_mfma_f32_16x16x32_f16(a, bfr, acc[ni], 0, 0, 0);
    }
  }
  int dm = m0 + w * 16 + ((lane >> 4) << 2);
  int dn0 = n0 + (lane & 15);
#pragma unroll
  for (int ni = 0; ni < 4; ni++) {
    int n = dn0 + ni * 16;
    float bv = bias ? bias[n] : 0.f;
#pragma unroll
    for (int r = 0; r < 4; r++) C[(size_t)(dm + r) * ldc + n] = acc[ni][r] + bv;
  }
}

// ---------------- K2: fused input-side GEMMs (giF | giB | giTok) + out[:,0,:] zero ----------------
__global__ __launch_bounds__(256) void k_gi(const f16* __restrict__ Xenc, const f16* __restrict__ Xdec,
                                            const f16* __restrict__ Wf, const f16* __restrict__ Wb,
                                            const f16* __restrict__ Wd,
                                            const float* __restrict__ bf, const float* __restrict__ bb,
                                            float* __restrict__ giF, float* __restrict__ giB,
                                            float* __restrict__ giTok, float* __restrict__ out) {
  int b = blockIdx.x;
  if (b < 384)      gemm_body(b & 31, b >> 5, Xenc, 256, Wf, 256, bf, giF, 768, 8);
  else if (b < 768) { b -= 384; gemm_body(b & 31, b >> 5, Xenc, 256, Wb, 256, bb, giB, 768, 8); }
  else if (b < 1512) { b -= 768; gemm_body(b % 31, b / 31, Xdec, 256, Wd, 768, nullptr, giTok, 1536, 8); }
  else {
    // zero out[:, 0, :]: 64 rows x 8000 float4 = 512000 float4; 125 blocks x 256 thr x 16
    long t = (long)(b - 1512) * 256 + threadIdx.x;
    float4 z = make_float4(0.f, 0.f, 0.f, 0.f);
#pragma unroll
    for (int k = 0; k < 16; k++) {
      long i = t * 16 + k;
      long bb = i / 8000, j = i % 8000;
      ((float4*)(out + bb * 1024000L))[j] = z;
    }
  }
}

// ---------------- K3: fused enc (WGs 0..15) + dec (WGs 16..47) ----------------
__device__ __forceinline__ void enc_body(
    f16* W,
    const float* __restrict__ giF, const float* __restrict__ giB,
    const f16* __restrict__ WhhF, const f16* __restrict__ WhhB,
    const float* __restrict__ bhhF, const float* __restrict__ bhhB,
    f16* __restrict__ hpp, f16* __restrict__ ctx16) {
  int wg = blockIdx.x;
  int dir = wg >> 3, ns = wg & 7;
  int tid = threadIdx.x, lane = tid & 63, wv = tid >> 6;
  int mTile = wv;
  const float* gi = dir ? giB : giF;
  const f16* Whh = dir ? WhhB : WhhF;
  const float* bhh = dir ? bhhB : bhhF;
  f16* hb = hpp + (size_t)dir * (32 * 64 * 256);
  int lo = lane & 15, hi = lane >> 4;
  int m = mTile * 16 + lo;
  int jb0 = ns * 32 + hi * 4;

#pragma unroll
  for (int c = 0; c < 12; c++) {
    int seg = c * 256 + tid;
    int row = seg >> 5, ck = seg & 31;
    int q = row >> 5, ii = row & 31;
    f16x8 v = *(const f16x8*)(Whh + (size_t)(q * 256 + ns * 32 + ii) * 256 + ck * 8);
    int col = (ck * 8) ^ ((row & 7) << 3);
    *(f16x8*)&W[row * 256 + col] = v;
  }
  __syncthreads();

  float4 bh[3][2];
#pragma unroll
  for (int q = 0; q < 3; q++)
#pragma unroll
    for (int i = 0; i < 2; i++)
      bh[q][i] = *(const float4*)(bhh + q * 256 + jb0 + i * 16);

  float4 ho[2] = {};
  float4 gcur[3][2];
  {
    int s0 = dir ? 31 : 0;
    const float* g0 = gi + (size_t)s0 * (64 * 768);
#pragma unroll
    for (int q = 0; q < 3; q++)
#pragma unroll
      for (int i = 0; i < 2; i++)
        gcur[q][i] = *(const float4*)(g0 + (size_t)m * 768 + q * 256 + jb0 + i * 16);
  }

  for (int s = 0; s < 32; s++) {
    // speculative burst: load own h[s] slice immediately; retry whole burst on sentinel
    V4 hv[8];
    const char* hb8 = (const char*)hb + ((size_t)s * 16384 + (size_t)m * 256 + hi * 8) * 2;
    for (;;) {
#pragma unroll
      for (int ks = 0; ks < 8; ks++)
        asm volatile("global_load_dwordx4 %0, %1, off offset:%2 sc0 sc1"
                     : "=&v"(hv[ks].u) : "v"(hb8), "i"(ks * 64));
      wait_vm0();
      unsigned bad = 0;
#pragma unroll
      for (int ks = 0; ks < 8; ks++) {
        bad |= ((hv[ks].u.x & hv[ks].u.y) == 0xFFFFFFFFu);
        bad |= ((hv[ks].u.z & hv[ks].u.w) == 0xFFFFFFFFu);
      }
      if (!__any((int)bad)) break;
      __builtin_amdgcn_s_sleep(1);
    }
    f32x4 acc[3][2] = {};
#pragma unroll
    for (int ks = 0; ks < 8; ks++) {
#pragma unroll
      for (int q = 0; q < 3; q++)
#pragma unroll
        for (int i = 0; i < 2; i++) {
          int row = q * 32 + i * 16 + lo;
          int col = (ks * 32 + hi * 8) ^ ((row & 7) << 3);
          f16x8 w = *(const f16x8*)&W[row * 256 + col];
          acc[q][i] = __builtin_amdgcn_mfma_f32_16x16x32_f16(w, hv[ks].h, acc[q][i], 0, 0, 0);
        }
    }
#pragma unroll
    for (int i = 0; i < 2; i++) {
      float hvv[4];
#pragma unroll
      for (int r2 = 0; r2 < 4; r2++) {
        float rg = sigmoidf_(((const float*)&gcur[0][i])[r2] + acc[0][i][r2] + ((const float*)&bh[0][i])[r2]);
        float zg = sigmoidf_(((const float*)&gcur[1][i])[r2] + acc[1][i][r2] + ((const float*)&bh[1][i])[r2]);
        float ng = tanhf_(((const float*)&gcur[2][i])[r2] + rg * (acc[2][i][r2] + ((const float*)&bh[2][i])[r2]));
        float hprev = ((const float*)&ho[i])[r2];
        hvv[r2] = (1.f - zg) * ng + zg * hprev;
        ((float*)&ho[i])[r2] = hvv[r2];
      }
      if (s < 31) sth4(hb + (size_t)(s + 1) * 16384 + m * 256 + jb0 + i * 16,
                       hvv[0], hvv[1], hvv[2], hvv[3]);
    }
    if (s < 31) {
      int sn = s + 1;
      int sgin = dir ? (31 - sn) : sn;
      const float* gs = gi + (size_t)sgin * (64 * 768);
#pragma unroll
      for (int q = 0; q < 3; q++)
#pragma unroll
        for (int i = 0; i < 2; i++)
          gcur[q][i] = *(const float4*)(gs + (size_t)m * 768 + q * 256 + jb0 + i * 16);
    }
  }
  // final context -> ctx16 via agent-scope 8B atomic stores (dec spins on these)
#pragma unroll
  for (int i = 0; i < 2; i++) {
    int c = dir * 256 + jb0 + i * 16;
    sth4(ctx16 + m * 512 + c, ((const float*)&ho[i])[0], ((const float*)&ho[i])[1],
         ((const float*)&ho[i])[2], ((const float*)&ho[i])[3]);
  }
}

__device__ __forceinline__ void dec_body(
    f16* W,
    const float* __restrict__ giTok, const f16* __restrict__ Wihd, const float* __restrict__ bihd,
    const f16* __restrict__ Whh, const float* __restrict__ bhh,
    const f16* __restrict__ ctx16, f16* __restrict__ Hall) {
  int cg = blockIdx.x - 16;
  int tid = threadIdx.x, lane = tid & 63, wv = tid >> 6;
  int mTile = wv;
  int lo = lane & 15, hi = lane >> 4;
  int koff = hi * 8;
  int m = mTile * 16 + lo;
  int j0 = cg * 16 + hi * 4;

  // stage weights (independent of enc -> overlaps encoder execution)
#pragma unroll
  for (int c = 0; c < 12; c++) {
    int seg = c * 256 + tid;
    int row = seg >> 6, ck = seg & 63;
    int q = row >> 4, ii = row & 15;
    f16x8 v = *(const f16x8*)(Whh + (size_t)(q * 512 + cg * 16 + ii) * 512 + ck * 8);
    int col = (ck * 8) ^ ((row & 7) << 3);
    *(f16x8*)&W[row * 512 + col] = v;
  }
  // biases + t=0 gi (independent of enc)
  float bi0[4], bi1[4], bi2[4], bh0[4], bh1[4], bhn[4];
#pragma unroll
  for (int r2 = 0; r2 < 4; r2++) {
    bi0[r2] = bihd[j0 + r2];        bh0[r2] = bhh[j0 + r2];
    bi1[r2] = bihd[512 + j0 + r2];  bh1[r2] = bhh[512 + j0 + r2];
    bi2[r2] = bihd[1024 + j0 + r2]; bhn[r2] = bhh[1024 + j0 + r2];
  }
  float4 gcur[3];
#pragma unroll
  for (int q = 0; q < 3; q++)
    gcur[q] = *(const float4*)(giTok + (size_t)m * 1536 + q * 512 + j0);
  __syncthreads();                        // weights staged

  // wait for ctx16 row m: speculative burst + sentinel retry (long-wait backoff)
  V4 hv[16];
  {
    const char* cb8 = (const char*)ctx16 + ((size_t)m * 512 + hi * 8) * 2;
    for (;;) {
#pragma unroll
      for (int ks = 0; ks < 16; ks++)
        asm volatile("global_load_dwordx4 %0, %1, off offset:%2 sc0 sc1"
                     : "=&v"(hv[ks].u) : "v"(cb8), "i"(ks * 64));
      wait_vm0();
      unsigned bad = 0;
#pragma unroll
      for (int ks = 0; ks < 16; ks++) {
        bad |= ((hv[ks].u.x & hv[ks].u.y) == 0xFFFFFFFFu);
        bad |= ((hv[ks].u.z & hv[ks].u.w) == 0xFFFFFFFFu);
      }
      if (!__any((int)bad)) break;
      __builtin_amdgcn_s_sleep(32);
    }
  }
  // ho init from ctx16 (f16-derived; one-time rounding, within tolerance)
  float4 ho;
  {
    u64 hoq;
    const u64* hp = (const u64*)(ctx16 + (size_t)m * 512 + j0);
    asm volatile("global_load_dwordx2 %0, %1, off sc0 sc1" : "=v"(hoq) : "v"(hp));
    asm volatile("s_waitcnt vmcnt(0)" ::: "memory");
    union { u64 u; f16 h[4]; } hu; hu.u = hoq;
    ho = make_float4((float)hu.h[0], (float)hu.h[1], (float)hu.h[2], (float)hu.h[3]);
  }
  // giCtx = ctx @ W_ihd[:,256:].T via MFMA (reuses hv as the A-operand)
  f32x4 acx[3] = {};
#pragma unroll
  for (int ks = 0; ks < 16; ks++) {
#pragma unroll
    for (int q = 0; q < 3; q++) {
      f16x8 w = *(const f16x8*)(Wihd + (size_t)(q * 512 + cg * 16 + lo) * 768 + 256 + ks * 32 + koff);
      acx[q] = __builtin_amdgcn_mfma_f32_16x16x32_f16(w, hv[ks].h, acx[q], 0, 0, 0);
    }
  }
  float b0[4], b1[4], bo2[4];
#pragma unroll
  for (int r2 = 0; r2 < 4; r2++) {
    b0[r2]  = acx[0][r2] + bi0[r2] + bh0[r2];
    b1[r2]  = acx[1][r2] + bi1[r2] + bh1[r2];
    bo2[r2] = acx[2][r2] + bi2[r2];
  }

  const int pj = lane >> 1;
  const int prow = mTile * 16 + (lane & 1) * 8;

  for (int t = 0; t < 31; t++) {
    if (t > 0) {
      // 1) cheap readiness probe (512B per wave per pass)
      {
        const u64* gp = (const u64*)(Hall + (size_t)(t - 1) * 32768) + (size_t)prow * 128 + pj * 4;
        for (;;) {
          u64 v;
          asm volatile("global_load_dwordx2 %0, %1, off sc0 sc1" : "=v"(v) : "v"(gp));
          asm volatile("s_waitcnt vmcnt(0)" ::: "memory");
          if (__all((int)(v != SENT))) break;
          __builtin_amdgcn_s_sleep(1);
        }
        __builtin_amdgcn_sched_barrier(0);
      }
      // 2) full burst, sentinel-validated
      const char* hb8 = (const char*)Hall + ((size_t)(t - 1) * 32768 + (size_t)m * 512 + hi * 8) * 2;
      for (;;) {
#pragma unroll
        for (int ks = 0; ks < 16; ks++)
          asm volatile("global_load_dwordx4 %0, %1, off offset:%2 sc0 sc1"
                       : "=&v"(hv[ks].u) : "v"(hb8), "i"(ks * 64));
        wait_vm0();
        unsigned bad = 0;
#pragma unroll
        for (int ks = 0; ks < 16; ks++) {
          bad |= ((hv[ks].u.x & hv[ks].u.y) == 0xFFFFFFFFu);
          bad |= ((hv[ks].u.z & hv[ks].u.w) == 0xFFFFFFFFu);
        }
        if (!__any((int)bad)) break;
        __builtin_amdgcn_s_sleep(1);
      }
    }
    f32x4 acc[3] = {};
#pragma unroll
    for (int ks = 0; ks < 16; ks++) {
#pragma unroll
      for (int q = 0; q < 3; q++) {
        int row = q * 16 + lo;
        int col = (ks * 32 + hi * 8) ^ ((row & 7) << 3);
        f16x8 w = *(const f16x8*)&W[row * 512 + col];
        acc[q] = __builtin_amdgcn_mfma_f32_16x16x32_f16(w, hv[ks].h, acc[q], 0, 0, 0);
      }
    }
    float hvv[4];
#pragma unroll
    for (int r2 = 0; r2 < 4; r2++) {
      float rg = sigmoidf_(((const float*)&gcur[0])[r2] + acc[0][r2] + b0[r2]);
      float zg = sigmoidf_(((const float*)&gcur[1])[r2] + acc[1][r2] + b1[r2]);
      float ng = tanhf_(((const float*)&gcur[2])[r2] + bo2[r2] + rg * (acc[2][r2] + bhn[r2]));
      float hprev = ((const float*)&ho)[r2];
      hvv[r2] = (1.f - zg) * ng + zg * hprev;
      ((float*)&ho)[r2] = hvv[r2];
    }
    sth4(Hall + (size_t)t * 32768 + (size_t)m * 512 + j0, hvv[0], hvv[1], hvv[2], hvv[3]);
    // prefetch next token-gi (overlaps store latency + next poll)
    {
      int tn = (t + 1 < 31) ? t + 1 : 30;
      const float* gs = giTok + (size_t)tn * (64 * 1536);
#pragma unroll
      for (int q = 0; q < 3; q++)
        gcur[q] = *(const float4*)(gs + (size_t)m * 1536 + q * 512 + j0);
    }
  }
}

__global__ __launch_bounds__(256, 1) void k_encdec(
    const float* __restrict__ giF, const float* __restrict__ giB,
    const f16* __restrict__ WhhF, const f16* __restrict__ WhhB,
    const float* __restrict__ bhhF, const float* __restrict__ bhhB,
    f16* __restrict__ hpp, f16* __restrict__ ctx16,
    const float* __restrict__ giTok, const f16* __restrict__ Wihd, const float* __restrict__ bihd,
    const f16* __restrict__ Whhd, const float* __restrict__ bhhd,
    f16* __restrict__ Hall) {
  __shared__ f16 W[96 * 256];   // 48KB: enc 96x256, dec 48x512 (same size)
  if (blockIdx.x < 16)
    enc_body(W, giF, giB, WhhF, WhhB, bhhF, bhhB, hpp, ctx16);
  else
    dec_body(W, giTok, Wihd, bihd, Whhd, bhhd, ctx16, Hall);
}

// ---------------- K4: FC GEMM (m97 staging, col-grouped, scalar NT stores; 3 blocks/CU) ----------------
__global__ __launch_bounds__(256, 3) void k_fc(const f16* __restrict__ Hall, const f16* __restrict__ Wfc,
                                               const float* __restrict__ fcb, float* __restrict__ out) {
  __shared__ f16 As[128 * 64];
  __shared__ f16 Bs[128 * 64];
  int bid = blockIdx.x;
  int bx = bid >> 4;                     // 0..249  column block
  int by = bid & 15;                     // 0..15   row block
  int m0 = by * 128, n0 = bx * 128;
  int tid = threadIdx.x, lane = tid & 63, wv = tid >> 6;
  int wm = wv >> 1, wn = wv & 1;
  int lo = lane & 15, hi = lane >> 4;
  int srow = lane >> 3, scol = (lane & 7) * 8;
  f32x4 acc[4][4] = {};
  for (int kk = 0; kk < 8; kk++) {
    if (kk) __syncthreads();
#pragma unroll
    for (int c4 = 0; c4 < 4; c4++) {
      int c = wv * 4 + c4;
      const f16* sA = Hall + (size_t)(m0 + c * 8 + srow) * 512 + kk * 64 + scol;
      const f16* sB = Wfc  + (size_t)(n0 + c * 8 + srow) * 512 + kk * 64 + scol;
      __builtin_amdgcn_global_load_lds((gbl_t*)sA, (lds_t*)&As[c * 512], 16, 0, 0);
      __builtin_amdgcn_global_load_lds((gbl_t*)sB, (lds_t*)&Bs[c * 512], 16, 0, 0);
    }
    __syncthreads();
#pragma unroll
    for (int ks = 0; ks < 2; ks++) {
      f16x8 af[4], bf[4];
#pragma unroll
      for (int mi = 0; mi < 4; mi++)
        af[mi] = *(const f16x8*)&As[(wm * 64 + mi * 16 + lo) * 64 + ks * 32 + hi * 8];
#pragma unroll
      for (int ni = 0; ni < 4; ni++)
        bf[ni] = *(const f16x8*)&Bs[(wn * 64 + ni * 16 + lo) * 64 + ks * 32 + hi * 8];
#pragma unroll
      for (int mi = 0; mi < 4; mi++) {
#pragma unroll
        for (int ni = 0; ni < 4; ni++)
          acc[mi][ni] = __builtin_amdgcn_mfma_f32_16x16x32_f16(af[mi], bf[ni], acc[mi][ni], 0, 0, 0);
      }
    }
  }
  int dn0 = n0 + wn * 64 + lo;
  float bv[4];
#pragma unroll
  for (int ni = 0; ni < 4; ni++) bv[ni] = fcb[dn0 + ni * 16];
#pragma unroll
  for (int mi = 0; mi < 4; mi++) {
    int mbase = m0 + wm * 64 + mi * 16 + (hi << 2);
#pragma unroll
    for (int rr = 0; rr < 4; rr++) {
      int mm = mbase + rr;
      if (mm < 1984) {
        int t = mm >> 6, bb = mm & 63;
        float* orow = out + (size_t)bb * 1024000 + (size_t)(t + 1) * 32000;
#pragma unroll
        for (int ni = 0; ni < 4; ni++)
          __builtin_nontemporal_store(acc[mi][ni][rr] + bv[ni], orow + dn0 + ni * 16);
      }
    }
  }
}

extern "C" void kernel_launch(void* const* d_in, const int* in_sizes, int n_in,
                              void* d_out, int out_size, void* d_ws, size_t ws_size,
                              hipStream_t stream) {
  const int*   srct = (const int*)d_in[0];
  const int*   trgt = (const int*)d_in[1];
  const float* embe = (const float*)d_in[2];
  const float* wihf = (const float*)d_in[3];
  const float* whhf = (const float*)d_in[4];
  const float* bihf = (const float*)d_in[5];
  const float* bhhf = (const float*)d_in[6];
  const float* wihb = (const float*)d_in[7];
  const float* whhb = (const float*)d_in[8];
  const float* bihb = (const float*)d_in[9];
  const float* bhhb = (const float*)d_in[10];
  const float* embd = (const float*)d_in[11];
  const float* wihd = (const float*)d_in[12];
  const float* whhd = (const float*)d_in[13];
  const float* bihd = (const float*)d_in[14];
  const float* bhhd = (const float*)d_in[15];
  const float* fcw  = (const float*)d_in[16];
  const float* fcb  = (const float*)d_in[17];
  float* out = (float*)d_out;
  char* ws = (char*)d_ws;

  f16* W_ihf = (f16*)(ws + OFF_WIHF);
  f16* W_hhf = (f16*)(ws + OFF_WHHF);
  f16* W_ihb = (f16*)(ws + OFF_WIHB);
  f16* W_hhb = (f16*)(ws + OFF_WHHB);
  f16* W_ihd = (f16*)(ws + OFF_WIHD);
  f16* W_hhd = (f16*)(ws + OFF_WHHD);
  f16* Wfc   = (f16*)(ws + OFF_FCW);
  f16* Xenc  = (f16*)(ws + OFF_XENC);
  f16* Xdec  = (f16*)(ws + OFF_XDEC);
  float* giF   = (float*)(ws + OFF_GIF);
  float* giB   = (float*)(ws + OFF_GIB);
  float* giTok = (float*)(ws + OFF_GITOK);
  f16*   ctx16 = (f16*)(ws + OFF_CTX16);
  f16*   hpp   = (f16*)(ws + OFF_HPP);
  f16*   Hall  = (f16*)(ws + OFF_HALL);

  k_init<<<5696, 256, 0, stream>>>(srct, trgt, embe, embd,
                                   wihf, whhf, wihb, whhb, wihd, whhd, fcw,
                                   W_ihf, W_hhf, W_ihb, W_hhb, W_ihd, W_hhd, Wfc,
                                   Xenc, Xdec, hpp, Hall, ctx16);
  k_gi<<<1637, 256, 0, stream>>>(Xenc, Xdec, W_ihf, W_ihb, W_ihd, bihf, bihb,
                                 giF, giB, giTok, out);
  k_encdec<<<48, 256, 0, stream>>>(giF, giB, W_hhf, W_hhb, bhhf, bhhb, hpp, ctx16,
                                   giTok, W_ihd, bihd, W_hhd, bhhd, Hall);
  k_fc<<<4000, 256, 0, stream>>>(Hall, Wfc, fcb, out);
}